// Round 8
// baseline (842.650 us; speedup 1.0000x reference)
//
#include <hip/hip_runtime.h>

#define TT 512

typedef _Float16 f16;
typedef _Float16 f16x4 __attribute__((ext_vector_type(4)));
typedef _Float16 f16x8 __attribute__((ext_vector_type(8)));
typedef float    f32x4 __attribute__((ext_vector_type(4)));

#define MFMA(A, B, C) __builtin_amdgcn_mfma_f32_16x16x32_f16((A), (B), (C), 0, 0, 0)

#define LOG2E  1.44269504f
#define LOG2E2 2.88539008f

__device__ __forceinline__ float exp2_(float x){
#if __has_builtin(__builtin_amdgcn_exp2f)
    return __builtin_amdgcn_exp2f(x);
#else
    return exp2f(x);
#endif
}
__device__ __forceinline__ float rcp_(float x){
#if __has_builtin(__builtin_amdgcn_rcpf)
    return __builtin_amdgcn_rcpf(x);
#else
    return 1.0f/x;
#endif
}
__device__ __forceinline__ f16x8 ldw8s(const float* p, float s){
    f16x8 r;
    #pragma unroll
    for (int i = 0; i < 8; ++i) r[i] = (f16)(p[i]*s);
    return r;
}

// Gate pre-scaling: i/f/o rows by LOG2E, g rows by LOG2E2 (folded into W+b).
// Shared-rcp: sig(a)*tanh(b) = (1-Eb)/((1+Ea)(1+Eb)).
__device__ __forceinline__ void act4(const f32x4& zi, const f32x4& zf,
                                     const f32x4& zg, const f32x4& zo,
                                     float* c, f16x4& hn){
    #pragma unroll
    for (int j = 0; j < 4; ++j){
        float Ef = exp2_(-zf[j]);
        float Ei = exp2_(-zi[j]);
        float Eg = exp2_(-zg[j]);
        float Eo = exp2_(-zo[j]);
        float f_ = rcp_(1.0f + Ef);
        float ig = (1.0f - Eg) * rcp_((1.0f + Ei)*(1.0f + Eg));
        c[j] = fmaf(f_, c[j], ig);
        float Ec = exp2_(-(LOG2E2*c[j]));
        float h_ = (1.0f - Ec) * rcp_((1.0f + Eo)*(1.0f + Ec));
        hn[j] = (f16)h_;
    }
}

#define LDS_FENCE() __asm__ volatile("s_waitcnt lgkmcnt(0)" ::: "memory")
#define MEMBAR()    __asm__ volatile("" ::: "memory")

// Counter layout (int cnt[16], 16B blocks, one block per consumer group):
//  [0]=AL1  [1]=CL1   |  [4]=AL1b [5]=AL2 [6]=CL2  |  [8]=AL2b [9]=AL3 [10]=CL3
//  [12]=AL3b
// Producers (after data write + fence, parallel lanes):
//  L1 wave: l0->AL1, l1->AL1b
//  L2 wave: l0->AL2, l1->AL2b, l2->CL1 (early, after input reads)
//  L3 wave: l0->AL3, l1->AL3b, l2->CL2 (early)
//  FC wave: l0->CL3 (early)
// 128 blocks x 832 threads (13 waves), 8 batch per block.
//  waves 0-3: L1   waves 4-7: L2   waves 8-11: L3   wave 12: FC (both tiles)
// h rings: [layer][slot=t&3][8b][64u] f16 XOR-swizzled. NO barrier in loop.
__global__ __launch_bounds__(832, 1) void lstm3_wavepipe2(
    const float* __restrict__ x,
    const float* __restrict__ w_ih1, const float* __restrict__ w_hh1, const float* __restrict__ b1,
    const float* __restrict__ w_ih2, const float* __restrict__ w_hh2, const float* __restrict__ b2,
    const float* __restrict__ w_ih3, const float* __restrict__ w_hh3, const float* __restrict__ b3,
    const float* __restrict__ fc1_w, const float* __restrict__ fc1_b,
    const float* __restrict__ fc2_w, const float* __restrict__ fc2_b,
    float* __restrict__ out)
{
    __shared__ __align__(16) unsigned char hring[3*4*1024];
    __shared__ float x_lds[TT*9];
    __shared__ __align__(16) int cnt[16];

    const int tid = threadIdx.x;
    const int wid = tid >> 6;
    const int l   = tid & 63;
    const int q   = l >> 4;
    const int bb  = l & 15;
    const int b8  = bb & 7;
    const int b0  = blockIdx.x * 8;
    const int role = wid >> 2;        // 0=L1 1=L2 2=L3 3=FC(wave 12)
    const int uq   = wid & 3;

    for (int i = tid; i < 8*TT; i += 832){
        int b = i >> 9, t = i & (TT-1);
        x_lds[t*9 + b] = x[(size_t)(b0+b)*TT + t];
    }
    for (int i = tid; i < (int)sizeof(hring)/4; i += 832)
        ((unsigned int*)hring)[i] = 0u;
    if (tid < 16) cnt[tid] = 0;

    // ---- persistent weights ----
    f16x8 wI[4][2], wH[4][2];
    float bcr[16], wih1r[16];
    if (role < 3){
        const float* Wih = (role == 1) ? w_ih2 : w_ih3;
        const float* Whh = (role == 0) ? w_hh1 : (role == 1 ? w_hh2 : w_hh3);
        const float* bp  = (role == 0) ? b1   : (role == 1 ? b2    : b3);
        #pragma unroll
        for (int g = 0; g < 4; ++g){
            const float sg = (g == 2) ? LOG2E2 : LOG2E;
            const int row = g*64 + uq*16 + bb;
            #pragma unroll
            for (int kh = 0; kh < 2; ++kh){
                wH[g][kh] = ldw8s(Whh + row*64 + kh*32 + q*8, sg);
                if (role != 0) wI[g][kh] = ldw8s(Wih + row*64 + kh*32 + q*8, sg);
            }
            #pragma unroll
            for (int j = 0; j < 4; ++j){
                const int rj = g*64 + uq*16 + 4*q + j;
                bcr[g*4+j] = bp[rj]*sg;
                if (role == 0) wih1r[g*4+j] = w_ih1[rj]*sg;
            }
        }
    } else {
        // FC weights reuse wI/bcr register space (no extra pressure):
        // wI[ti][kh] = fc1_w tile ti; bcr[0..7]=fc1_b; bcr[8..15]=fc2_w
        #pragma unroll
        for (int ti = 0; ti < 2; ++ti){
            #pragma unroll
            for (int kh = 0; kh < 2; ++kh)
                wI[ti][kh] = ldw8s(fc1_w + (ti*16 + bb)*64 + kh*32 + q*8, 1.0f);
            #pragma unroll
            for (int j = 0; j < 4; ++j){
                bcr[ti*4+j]     = fc1_b[ti*16 + 4*q + j];
                bcr[8 + ti*4+j] = fc2_w[ti*16 + 4*q + j];
            }
        }
    }
    const float fc2bs = fc2_b[0];

    float c[4] = {0.f, 0.f, 0.f, 0.f};
    float obuf0 = 0.f, obuf1 = 0.f, obuf2 = 0.f;

    const int rowb = b8*128;
    const int swz  = 16*b8;
    const int rdA  = rowb + ((16*q     ) ^ swz);
    const int rdB  = rowb + ((16*q + 64) ^ swz);
    const int wro  = rowb + ((uq*32 + 8*q) ^ swz);

    const f32x4 vzero = {0.f, 0.f, 0.f, 0.f};

    __syncthreads();   // only block-wide barrier

    if (role == 0){
        #pragma unroll 1
        for (int t = 0; t < TT; ++t){
            {   // AL1 >= 4t (peers t-1), CL1 >= 4(t-3) (ring free)
                const volatile int* vp = (const volatile int*)&cnt[0];
                while ((vp[0] < 4*t) | (vp[1] < 4*(t-3))) {}
            }
            MEMBAR();
            const unsigned char* hr = hring + ((t-1)&3)*1024;
            unsigned char*       hw = hring + ((t  )&3)*1024;
            const f16x8 hA = *(const f16x8*)(hr + rdA);
            const f16x8 hB = *(const f16x8*)(hr + rdB);
            const float xv = x_lds[t*9 + b8];
            f32x4 p0, p1, p2, p3, q0, q1, q2, q3;
            #pragma unroll
            for (int j = 0; j < 4; ++j){
                p0[j] = fmaf(wih1r[j],    xv, bcr[j]);
                p1[j] = fmaf(wih1r[4+j],  xv, bcr[4+j]);
                p2[j] = fmaf(wih1r[8+j],  xv, bcr[8+j]);
                p3[j] = fmaf(wih1r[12+j], xv, bcr[12+j]);
            }
            p0 = MFMA(wH[0][0], hA, p0); p1 = MFMA(wH[1][0], hA, p1);
            p2 = MFMA(wH[2][0], hA, p2); p3 = MFMA(wH[3][0], hA, p3);
            q0 = MFMA(wH[0][1], hB, vzero); q1 = MFMA(wH[1][1], hB, vzero);
            q2 = MFMA(wH[2][1], hB, vzero); q3 = MFMA(wH[3][1], hB, vzero);
            f32x4 a0 = p0+q0, a1 = p1+q1, a2 = p2+q2, a3 = p3+q3;
            f16x4 hn;
            act4(a0, a1, a2, a3, c, hn);
            if (bb < 8) *(f16x4*)(hw + wro) = hn;
            LDS_FENCE();
            if (l == 0) atomicAdd(&cnt[0], 1);       // AL1
            else if (l == 1) atomicAdd(&cnt[4], 1);  // AL1b
        }
    } else if (role < 3){
        const int cbase = (role == 1) ? 4 : 8;
        const int cinid = (role == 1) ? 1 : 6;       // CL1 / CL2
        const int amyid = (role == 1) ? 5 : 9;       // AL2 / AL3
        const int amybd = (role == 1) ? 8 : 12;      // AL2b / AL3b
        #pragma unroll 1
        for (int t = 0; t < TT; ++t){
            {   // in >= 4(t+1), my >= 4t, consumed >= target
                const int tcl = (role == 1) ? 4*(t-3) : (t-3);
                const volatile int* vp = (const volatile int*)&cnt[cbase];
                while ((vp[0] < 4*(t+1)) | (vp[1] < 4*t) | (vp[2] < tcl)) {}
            }
            MEMBAR();
            const unsigned char* ir = hring + (role-1)*4096 + ((t  )&3)*1024;
            const unsigned char* hr = hring + (role  )*4096 + ((t-1)&3)*1024;
            unsigned char*       hw = hring + (role  )*4096 + ((t  )&3)*1024;
            const f16x8 iA = *(const f16x8*)(ir + rdA);
            const f16x8 iB = *(const f16x8*)(ir + rdB);
            const f16x8 hA = *(const f16x8*)(hr + rdA);
            const f16x8 hB = *(const f16x8*)(hr + rdB);
            LDS_FENCE();
            if (l == 2) atomicAdd(&cnt[cinid], 1);   // consumed input, early
            f32x4 p0, p1, p2, p3, q0, q1, q2, q3;
            #pragma unroll
            for (int j = 0; j < 4; ++j){
                p0[j] = bcr[j]; p1[j] = bcr[4+j]; p2[j] = bcr[8+j]; p3[j] = bcr[12+j];
            }
            p0 = MFMA(wI[0][0], iA, p0); p1 = MFMA(wI[1][0], iA, p1);
            p2 = MFMA(wI[2][0], iA, p2); p3 = MFMA(wI[3][0], iA, p3);
            q0 = MFMA(wI[0][1], iB, vzero); q1 = MFMA(wI[1][1], iB, vzero);
            q2 = MFMA(wI[2][1], iB, vzero); q3 = MFMA(wI[3][1], iB, vzero);
            p0 = MFMA(wH[0][0], hA, p0); p1 = MFMA(wH[1][0], hA, p1);
            p2 = MFMA(wH[2][0], hA, p2); p3 = MFMA(wH[3][0], hA, p3);
            q0 = MFMA(wH[0][1], hB, q0); q1 = MFMA(wH[1][1], hB, q1);
            q2 = MFMA(wH[2][1], hB, q2); q3 = MFMA(wH[3][1], hB, q3);
            f32x4 a0 = p0+q0, a1 = p1+q1, a2 = p2+q2, a3 = p3+q3;
            f16x4 hn;
            act4(a0, a1, a2, a3, c, hn);
            if (bb < 8) *(f16x4*)(hw + wro) = hn;
            LDS_FENCE();
            if (l == 0) atomicAdd(&cnt[amyid], 1);
            else if (l == 1) atomicAdd(&cnt[amybd], 1);
        }
    } else {
        // ---------------- FC wave (wid 12): both tiles, direct store ----------------
        #pragma unroll 1
        for (int tf = 0; tf < TT; ++tf){
            {   const volatile int* vp = (const volatile int*)&cnt[12];
                while (vp[0] < 4*(tf+1)) {}          // AL3b: h3(tf) ready
            }
            MEMBAR();
            const unsigned char* h3r = hring + 2*4096 + (tf&3)*1024;
            const f16x8 pA = *(const f16x8*)(h3r + rdA);
            const f16x8 pB = *(const f16x8*)(h3r + rdB);
            LDS_FENCE();
            if (l == 0) atomicAdd(&cnt[10], 1);      // CL3, early
            f32x4 y0p, y1p, y0q, y1q;
            #pragma unroll
            for (int j = 0; j < 4; ++j){ y0p[j] = bcr[j]; y1p[j] = bcr[4+j]; }
            y0p = MFMA(wI[0][0], pA, y0p); y0q = MFMA(wI[0][1], pB, vzero);
            y1p = MFMA(wI[1][0], pA, y1p); y1q = MFMA(wI[1][1], pB, vzero);
            f32x4 y0 = y0p + y0q, y1 = y1p + y1q;
            float s = 0.f;
            #pragma unroll
            for (int j = 0; j < 4; ++j){
                float u = fmaxf(y0[j], 0.2f*y0[j]);  // leaky_relu(0.2)
                s = fmaf(u, bcr[8+j], s);
                float v = fmaxf(y1[j], 0.2f*y1[j]);
                s = fmaf(v, bcr[12+j], s);
            }
            s += __shfl_xor(s, 16);
            s += __shfl_xor(s, 32);
            s += fc2bs;
            const int ph = tf & 3;
            if (ph == 0) obuf0 = s;
            else if (ph == 1) obuf1 = s;
            else if (ph == 2) obuf2 = s;
            else if (l < 8){
                float4 v4 = make_float4(obuf0, obuf1, obuf2, s);
                *(float4*)(out + (size_t)(b0+l)*TT + (tf - 3)) = v4;
            }
        }
    }
}

extern "C" void kernel_launch(void* const* d_in, const int* in_sizes, int n_in,
                              void* d_out, int out_size, void* d_ws, size_t ws_size,
                              hipStream_t stream)
{
    (void)in_sizes; (void)n_in; (void)d_ws; (void)ws_size; (void)out_size;
    const float* x     = (const float*)d_in[0];
    const float* w_ih1 = (const float*)d_in[1];
    const float* w_hh1 = (const float*)d_in[2];
    const float* b1    = (const float*)d_in[3];
    const float* w_ih2 = (const float*)d_in[4];
    const float* w_hh2 = (const float*)d_in[5];
    const float* b2    = (const float*)d_in[6];
    const float* w_ih3 = (const float*)d_in[7];
    const float* w_hh3 = (const float*)d_in[8];
    const float* b3    = (const float*)d_in[9];
    const float* fc1_w = (const float*)d_in[10];
    const float* fc1_b = (const float*)d_in[11];
    const float* fc2_w = (const float*)d_in[12];
    const float* fc2_b = (const float*)d_in[13];

    lstm3_wavepipe2<<<dim3(128), dim3(832), 0, stream>>>(
        x, w_ih1, w_hh1, b1, w_ih2, w_hh2, b2, w_ih3, w_hh3, b3,
        fc1_w, fc1_b, fc2_w, fc2_b, (float*)d_out);
}

// Round 9
// 804.960 us; speedup vs baseline: 1.0468x; 1.0468x over previous
//
#include <hip/hip_runtime.h>

#define TT 512

typedef _Float16 f16;
typedef _Float16 f16x4 __attribute__((ext_vector_type(4)));
typedef _Float16 f16x8 __attribute__((ext_vector_type(8)));
typedef float    f32x4 __attribute__((ext_vector_type(4)));

#define MFMA(A, B, C) __builtin_amdgcn_mfma_f32_16x16x32_f16((A), (B), (C), 0, 0, 0)

#define LOG2E  1.44269504f
#define LOG2E2 2.88539008f

__device__ __forceinline__ float exp2_(float x){
#if __has_builtin(__builtin_amdgcn_exp2f)
    return __builtin_amdgcn_exp2f(x);
#else
    return exp2f(x);
#endif
}
__device__ __forceinline__ float rcp_(float x){
#if __has_builtin(__builtin_amdgcn_rcpf)
    return __builtin_amdgcn_rcpf(x);
#else
    return 1.0f/x;
#endif
}
__device__ __forceinline__ f16x8 ldw8s(const float* p, float s){
    f16x8 r;
    #pragma unroll
    for (int i = 0; i < 8; ++i) r[i] = (f16)(p[i]*s);
    return r;
}

// Gate pre-scaling: i/f/o rows by LOG2E, g rows by LOG2E2 (folded into W+b).
// Shared-rcp: sig(a)*tanh(b) = (1-Eb)/((1+Ea)(1+Eb)).
__device__ __forceinline__ void act4(const f32x4& zi, const f32x4& zf,
                                     const f32x4& zg, const f32x4& zo,
                                     float* c, f16x4& hn){
    #pragma unroll
    for (int j = 0; j < 4; ++j){
        float Ef = exp2_(-zf[j]);
        float Ei = exp2_(-zi[j]);
        float Eg = exp2_(-zg[j]);
        float Eo = exp2_(-zo[j]);
        float f_ = rcp_(1.0f + Ef);
        float ig = (1.0f - Eg) * rcp_((1.0f + Ei)*(1.0f + Eg));
        c[j] = fmaf(f_, c[j], ig);
        float Ec = exp2_(-(LOG2E2*c[j]));
        float h_ = (1.0f - Ec) * rcp_((1.0f + Eo)*(1.0f + Ec));
        hn[j] = (f16)h_;
    }
}

#define LDS_FENCE() __asm__ volatile("s_waitcnt lgkmcnt(0)" ::: "memory")
#define MEMBAR()    __asm__ volatile("" ::: "memory")

// Packed-counter polls: one ds_read_b128 per iteration.
__device__ __forceinline__ void poll2(const int* base, int a, int b){
    for(;;){ MEMBAR(); int4 v = *(const int4*)base; if (v.x>=a && v.y>=b) break; }
    MEMBAR();
}
__device__ __forceinline__ void poll3(const int* base, int a, int b, int c_){
    for(;;){ MEMBAR(); int4 v = *(const int4*)base; if (v.x>=a && v.y>=b && v.z>=c_) break; }
    MEMBAR();
}
__device__ __forceinline__ void poll4(const int* base, int a, int b, int c_, int d_){
    for(;;){ MEMBAR(); int4 v = *(const int4*)base;
             if (v.x>=a && v.y>=b && v.z>=c_ && v.w>=d_) break; }
    MEMBAR();
}

// Counter map (16B blocks; one block per consumer group):
//  block0 @cnt[0] (L1 poll):  [0]=AL1  [1]=CL1
//  block1 @cnt[4] (L2 poll):  [4]=AL1b [5]=AL2  [6]=CL2
//  block2 @cnt[8] (L3 poll):  [8]=AL2b [9]=AL3  [10]=AF0 [11]=AF1
// Producers: L1 end: l0->AL1, l1->AL1b.
//            L2: after input fence l2->CL1; end: l0->AL2, l1->AL2b.
//            L3: after input fence l1->CL2; end: l0->AL3.
//            L3-uq0/uq1 after s_fc write: l2->AF0/AF1.
// 128 blocks x 768 threads (12 waves), 8 batch per block. NO barrier in loop.
//  waves 0-3: L1   waves 4-7: L2   waves 8-11: L3 (+FC on uq0/uq1, store on uq2)
__global__ __launch_bounds__(768, 1) void lstm3_wavepipe3(
    const float* __restrict__ x,
    const float* __restrict__ w_ih1, const float* __restrict__ w_hh1, const float* __restrict__ b1,
    const float* __restrict__ w_ih2, const float* __restrict__ w_hh2, const float* __restrict__ b2,
    const float* __restrict__ w_ih3, const float* __restrict__ w_hh3, const float* __restrict__ b3,
    const float* __restrict__ fc1_w, const float* __restrict__ fc1_b,
    const float* __restrict__ fc2_w, const float* __restrict__ fc2_b,
    float* __restrict__ out)
{
    __shared__ __align__(16) unsigned char hring[3*4*1024];  // [layer][slot][8b][64u] f16 swz
    __shared__ float x_lds[TT*9];
    __shared__ float s_fc[2][4][8];                          // [tile][slot][batch]
    __shared__ __align__(16) int cnt[16];

    const int tid = threadIdx.x;
    const int wid = tid >> 6;
    const int l   = tid & 63;
    const int q   = l >> 4;
    const int bb  = l & 15;
    const int b8  = bb & 7;
    const int b0  = blockIdx.x * 8;
    const int role = wid >> 2;        // 0=L1 1=L2 2=L3
    const int uq   = wid & 3;

    for (int i = tid; i < 8*TT; i += 768){
        int b = i >> 9, t = i & (TT-1);
        x_lds[t*9 + b] = x[(size_t)(b0+b)*TT + t];
    }
    for (int i = tid; i < (int)sizeof(hring)/4; i += 768)
        ((unsigned int*)hring)[i] = 0u;
    if (tid < 16) cnt[tid] = 0;
    if (tid < 64) ((float*)s_fc)[tid] = 0.f;

    // ---- persistent weights (R4/R6-proven structure) ----
    const float* Wih = (role == 1) ? w_ih2 : w_ih3;
    const float* Whh = (role == 0) ? w_hh1 : (role == 1 ? w_hh2 : w_hh3);
    const float* bp  = (role == 0) ? b1   : (role == 1 ? b2    : b3);

    f16x8 wI[4][2], wH[4][2];
    float bcr[16], wih1r[16];
    #pragma unroll
    for (int g = 0; g < 4; ++g){
        const float sg = (g == 2) ? LOG2E2 : LOG2E;
        const int row = g*64 + uq*16 + bb;
        #pragma unroll
        for (int kh = 0; kh < 2; ++kh){
            wH[g][kh] = ldw8s(Whh + row*64 + kh*32 + q*8, sg);
            if (role != 0) wI[g][kh] = ldw8s(Wih + row*64 + kh*32 + q*8, sg);
        }
        #pragma unroll
        for (int j = 0; j < 4; ++j){
            const int rj = g*64 + uq*16 + 4*q + j;
            bcr[g*4+j] = bp[rj]*sg;
            if (role == 0) wih1r[g*4+j] = w_ih1[rj]*sg;
        }
    }

    // FC fragments: L3 waves uq0/uq1, one 16-col tile each
    f16x8 wfc[2];
    float fc1br[4], fc2wr[4];
    const float fc2bs = fc2_b[0];
    if (role == 2 && uq < 2){
        #pragma unroll
        for (int kh = 0; kh < 2; ++kh)
            wfc[kh] = ldw8s(fc1_w + (uq*16 + bb)*64 + kh*32 + q*8, 1.0f);
        #pragma unroll
        for (int j = 0; j < 4; ++j){
            fc1br[j] = fc1_b[uq*16 + 4*q + j];
            fc2wr[j] = fc2_w[uq*16 + 4*q + j];
        }
    }

    float c[4] = {0.f, 0.f, 0.f, 0.f};
    float obuf0 = 0.f, obuf1 = 0.f, obuf2 = 0.f;

    const int rowb = b8*128;
    const int swz  = 16*b8;
    const int rdA  = rowb + ((16*q     ) ^ swz);
    const int rdB  = rowb + ((16*q + 64) ^ swz);
    const int wro  = rowb + ((uq*32 + 8*q) ^ swz);

    const f32x4 vzero = {0.f, 0.f, 0.f, 0.f};

    __syncthreads();   // only block-wide barrier

    if (role == 0){
        #pragma unroll 1
        for (int t = 0; t < TT; ++t){
            poll2(&cnt[0], 4*t, 4*(t-3));            // AL1 peers(t-1), CL1 ring free
            const unsigned char* hr = hring + ((t-1)&3)*1024;
            unsigned char*       hw = hring + ((t  )&3)*1024;
            const f16x8 hA = *(const f16x8*)(hr + rdA);
            const f16x8 hB = *(const f16x8*)(hr + rdB);
            const float xv = x_lds[t*9 + b8];
            f32x4 p0, p1, p2, p3, q0, q1, q2, q3;
            #pragma unroll
            for (int j = 0; j < 4; ++j){
                p0[j] = fmaf(wih1r[j],    xv, bcr[j]);
                p1[j] = fmaf(wih1r[4+j],  xv, bcr[4+j]);
                p2[j] = fmaf(wih1r[8+j],  xv, bcr[8+j]);
                p3[j] = fmaf(wih1r[12+j], xv, bcr[12+j]);
            }
            p0 = MFMA(wH[0][0], hA, p0); p1 = MFMA(wH[1][0], hA, p1);
            p2 = MFMA(wH[2][0], hA, p2); p3 = MFMA(wH[3][0], hA, p3);
            q0 = MFMA(wH[0][1], hB, vzero); q1 = MFMA(wH[1][1], hB, vzero);
            q2 = MFMA(wH[2][1], hB, vzero); q3 = MFMA(wH[3][1], hB, vzero);
            f32x4 a0 = p0+q0, a1 = p1+q1, a2 = p2+q2, a3 = p3+q3;
            f16x4 hn;
            act4(a0, a1, a2, a3, c, hn);
            if (bb < 8) *(f16x4*)(hw + wro) = hn;
            LDS_FENCE();
            if (l == 0) atomicAdd(&cnt[0], 1);       // AL1
            else if (l == 1) atomicAdd(&cnt[4], 1);  // AL1b
        }
    } else if (role == 1){
        #pragma unroll 1
        for (int t = 0; t < TT; ++t){
            poll3(&cnt[4], 4*(t+1), 4*t, 4*(t-3));   // AL1b in, AL2 peers, CL2 ring
            const unsigned char* ir = hring +          ((t  )&3)*1024;
            const unsigned char* hr = hring + 4096  + ((t-1)&3)*1024;
            unsigned char*       hw = hring + 4096  + ((t  )&3)*1024;
            const f16x8 iA = *(const f16x8*)(ir + rdA);
            const f16x8 iB = *(const f16x8*)(ir + rdB);
            const f16x8 hA = *(const f16x8*)(hr + rdA);
            const f16x8 hB = *(const f16x8*)(hr + rdB);
            LDS_FENCE();
            if (l == 2) atomicAdd(&cnt[1], 1);       // CL1 (consumed h1(t)) early
            f32x4 p0, p1, p2, p3, q0, q1, q2, q3;
            #pragma unroll
            for (int j = 0; j < 4; ++j){
                p0[j] = bcr[j]; p1[j] = bcr[4+j]; p2[j] = bcr[8+j]; p3[j] = bcr[12+j];
            }
            p0 = MFMA(wI[0][0], iA, p0); p1 = MFMA(wI[1][0], iA, p1);
            p2 = MFMA(wI[2][0], iA, p2); p3 = MFMA(wI[3][0], iA, p3);
            q0 = MFMA(wI[0][1], iB, vzero); q1 = MFMA(wI[1][1], iB, vzero);
            q2 = MFMA(wI[2][1], iB, vzero); q3 = MFMA(wI[3][1], iB, vzero);
            p0 = MFMA(wH[0][0], hA, p0); p1 = MFMA(wH[1][0], hA, p1);
            p2 = MFMA(wH[2][0], hA, p2); p3 = MFMA(wH[3][0], hA, p3);
            q0 = MFMA(wH[0][1], hB, q0); q1 = MFMA(wH[1][1], hB, q1);
            q2 = MFMA(wH[2][1], hB, q2); q3 = MFMA(wH[3][1], hB, q3);
            f32x4 a0 = p0+q0, a1 = p1+q1, a2 = p2+q2, a3 = p3+q3;
            f16x4 hn;
            act4(a0, a1, a2, a3, c, hn);
            if (bb < 8) *(f16x4*)(hw + wro) = hn;
            LDS_FENCE();
            if (l == 0) atomicAdd(&cnt[5], 1);       // AL2
            else if (l == 1) atomicAdd(&cnt[8], 1);  // AL2b
        }
    } else {
        #pragma unroll 1
        for (int t = 0; t < TT + 2; ++t){
            const int tin = (t   < TT) ? t   : TT-1;   // clamp poll targets at end
            const int tmy = (t   < TT) ? t   : TT;
            if (uq == 2) poll4(&cnt[8], 4*(tin+1), 4*((tmy<TT)?tmy:TT), t-1, t-1);
            else         poll2(&cnt[8], 4*(tin+1), 4*((tmy<TT)?tmy:TT));
            if (t < TT){
                const unsigned char* ir = hring + 4096   + ((t  )&3)*1024;
                const unsigned char* hr = hring + 2*4096 + ((t-1)&3)*1024;
                unsigned char*       hw = hring + 2*4096 + ((t  )&3)*1024;
                const f16x8 iA = *(const f16x8*)(ir + rdA);
                const f16x8 iB = *(const f16x8*)(ir + rdB);
                const f16x8 hA = *(const f16x8*)(hr + rdA);
                const f16x8 hB = *(const f16x8*)(hr + rdB);
                LDS_FENCE();
                if (l == 1) atomicAdd(&cnt[6], 1);   // CL2 (consumed h2(t)) early
                f32x4 p0, p1, p2, p3, q0, q1, q2, q3;
                #pragma unroll
                for (int j = 0; j < 4; ++j){
                    p0[j] = bcr[j]; p1[j] = bcr[4+j]; p2[j] = bcr[8+j]; p3[j] = bcr[12+j];
                }
                p0 = MFMA(wI[0][0], iA, p0); p1 = MFMA(wI[1][0], iA, p1);
                p2 = MFMA(wI[2][0], iA, p2); p3 = MFMA(wI[3][0], iA, p3);
                q0 = MFMA(wI[0][1], iB, vzero); q1 = MFMA(wI[1][1], iB, vzero);
                q2 = MFMA(wI[2][1], iB, vzero); q3 = MFMA(wI[3][1], iB, vzero);
                p0 = MFMA(wH[0][0], hA, p0); p1 = MFMA(wH[1][0], hA, p1);
                p2 = MFMA(wH[2][0], hA, p2); p3 = MFMA(wH[3][0], hA, p3);
                q0 = MFMA(wH[0][1], hB, q0); q1 = MFMA(wH[1][1], hB, q1);
                q2 = MFMA(wH[2][1], hB, q2); q3 = MFMA(wH[3][1], hB, q3);
                f32x4 a0 = p0+q0, a1 = p1+q1, a2 = p2+q2, a3 = p3+q3;
                f16x4 hn;
                act4(a0, a1, a2, a3, c, hn);
                if (bb < 8) *(f16x4*)(hw + wro) = hn;
                LDS_FENCE();
                if (l == 0) atomicAdd(&cnt[9], 1);   // AL3
            }
            // ---- FC tile (uq0/uq1) @ tf = t-1 : h3(tf) complete per this poll ----
            if (uq < 2 && t >= 1 && t <= TT){
                const int tf = t - 1;
                const unsigned char* h3r = hring + 2*4096 + (tf&3)*1024;
                const f16x8 pA = *(const f16x8*)(h3r + rdA);
                const f16x8 pB = *(const f16x8*)(h3r + rdB);
                f32x4 yp, yq;
                #pragma unroll
                for (int j = 0; j < 4; ++j) yp[j] = fc1br[j];
                yp = MFMA(wfc[0], pA, yp);
                yq = MFMA(wfc[1], pB, vzero);
                f32x4 y = yp + yq;
                float s = 0.f;
                #pragma unroll
                for (int j = 0; j < 4; ++j){
                    float u = fmaxf(y[j], 0.2f*y[j]);   // leaky_relu(0.2)
                    s = fmaf(u, fc2wr[j], s);
                }
                s += __shfl_xor(s, 16);
                s += __shfl_xor(s, 32);
                if (l < 8) s_fc[uq][tf&3][l] = s;
                LDS_FENCE();
                if (l == 2) atomicAdd(&cnt[10 + uq], 1);  // AF0/AF1
            }
            // ---- combine + batched store (uq2) @ tc = t-2 ----
            if (uq == 2 && t >= 2){
                const int tc = t - 2;
                float s = 0.f;
                if (l < 8) s = s_fc[0][tc&3][l] + s_fc[1][tc&3][l] + fc2bs;
                const int ph = tc & 3;
                if (ph == 0) obuf0 = s;
                else if (ph == 1) obuf1 = s;
                else if (ph == 2) obuf2 = s;
                else if (l < 8){
                    float4 v4 = make_float4(obuf0, obuf1, obuf2, s);
                    *(float4*)(out + (size_t)(b0+l)*TT + (tc - 3)) = v4;
                }
            }
        }
    }
}

extern "C" void kernel_launch(void* const* d_in, const int* in_sizes, int n_in,
                              void* d_out, int out_size, void* d_ws, size_t ws_size,
                              hipStream_t stream)
{
    (void)in_sizes; (void)n_in; (void)d_ws; (void)ws_size; (void)out_size;
    const float* x     = (const float*)d_in[0];
    const float* w_ih1 = (const float*)d_in[1];
    const float* w_hh1 = (const float*)d_in[2];
    const float* b1    = (const float*)d_in[3];
    const float* w_ih2 = (const float*)d_in[4];
    const float* w_hh2 = (const float*)d_in[5];
    const float* b2    = (const float*)d_in[6];
    const float* w_ih3 = (const float*)d_in[7];
    const float* w_hh3 = (const float*)d_in[8];
    const float* b3    = (const float*)d_in[9];
    const float* fc1_w = (const float*)d_in[10];
    const float* fc1_b = (const float*)d_in[11];
    const float* fc2_w = (const float*)d_in[12];
    const float* fc2_b = (const float*)d_in[13];

    lstm3_wavepipe3<<<dim3(128), dim3(768), 0, stream>>>(
        x, w_ih1, w_hh1, b1, w_ih2, w_hh2, b2, w_ih3, w_hh3, b3,
        fc1_w, fc1_b, fc2_w, fc2_b, (float*)d_out);
}